// Round 13
// baseline (133.318 us; speedup 1.0000x reference)
//
#include <hip/hip_runtime.h>

// DCNv2 forward = prep (weight repack + NHWC transpose) + BARRIER-FREE fused
// im2col+GEMM: each wave owns 16 px end-to-end (coefs -> gather -> MFMA) in
// its private LDS slab. Zero __syncthreads in the main kernel -> waves are
// independent and the unrolled tap loop software-pipelines freely.
#define N_    4
#define C_    64
#define H_    128
#define W_    128
#define KW_   3
#define K_    9
#define COUT_ 64
#define HW_   (H_ * W_)     // 16384
#define NPIX  (N_ * HW_)    // 65536
#define KK_   (C_ * K_)     // 576

typedef short v8s __attribute__((ext_vector_type(8)));   // 8 bf16 (4 VGPRs)
typedef float v4f __attribute__((ext_vector_type(4)));   // MFMA C/D
typedef int   v4i __attribute__((ext_vector_type(4)));
typedef unsigned int u32;
typedef unsigned short u16;
typedef unsigned int v2u __attribute__((ext_vector_type(2)));

static __device__ __forceinline__ u16 f2bf(float f) {
    union { float f; unsigned int u; } v; v.f = f;
    unsigned int r = v.u + 0x7FFFu + ((v.u >> 16) & 1u);   // RNE
    return (u16)(r >> 16);
}
static __device__ __forceinline__ u32 pack2(float lo, float hi) {
    return ((u32)f2bf(hi) << 16) | (u32)f2bf(lo);
}

// ---------------------------------------------------------------------------
// prep: one dispatch doing both prologue jobs.
//   blocks 0..1023  : NCHW->NHWC fp32 transpose xh[n][hw][c] (LDS-tiled 64x64)
//   blocks 1024..1167: wA3[o][k] = bf16(weight[o][c][tap]), k = tap*64+c
// ---------------------------------------------------------------------------
__global__ __launch_bounds__(256) void prep(
    const float* __restrict__ x, float* __restrict__ xh,
    const float* __restrict__ w, u16* __restrict__ wA3)
{
    if (blockIdx.x < 1024) {
        const int n   = blockIdx.x >> 8;            // 4 images x 256 hw-tiles
        const int hw0 = (blockIdx.x & 255) * 64;
        const int j   = threadIdx.x & 63;           // lane
        const int r0  = threadIdx.x >> 6;           // 0..3

        __shared__ float tile[64][65];              // [hw][c], pad -> conflict-free
        const float* xb = x + n * (C_ * HW_);
#pragma unroll
        for (int i = 0; i < 16; ++i) {
            const int c = i * 4 + r0;
            tile[j][c] = xb[c * HW_ + hw0 + j];     // lane j = hw: coalesced 256B
        }
        __syncthreads();
        float* xo = xh + ((size_t)n * HW_ + hw0) * 64;
#pragma unroll
        for (int i = 0; i < 16; ++i) {
            const int hr = i * 4 + r0;
            xo[hr * 64 + j] = tile[hr][j];          // lane j = c: coalesced 256B
        }
    } else {
        const int tid = (blockIdx.x - 1024) * 256 + threadIdx.x;  // 0..36863
        if (tid < COUT_ * KK_) {
            const int k   = tid % KK_;              // tap*64 + c
            const int o   = tid / KK_;
            const int c   = k & 63;
            const int tap = k >> 6;
            wA3[tid] = f2bf(w[o * (C_ * K_) + c * K_ + tap]);
        }
    }
}

// ---------------------------------------------------------------------------
// Barrier-free fused im2col+GEMM. Block = 4 INDEPENDENT waves; each wave:
//   - 16 pixels, all 64 cout (4x 16x16x32 MFMA subtiles, 4 v4f acc)
//   - phase 1: coefs for its 16px x 9 taps -> private coefw slab
//     (wave-lockstep LDS: compiler lgkmcnt suffices, NO __syncthreads)
//   - per tap: quarter-wave gather (lane = (qtr, c4), float4 = 4 channels,
//     one instr covers 4 pixels' corner) -> private dbuf Bt slab -> 8 MFMA.
// Tap loop fully unrolled, buffers alternate at compile time: the scheduler
// hoists gather(t+1) loads above MFMA(t) — the pipeline R12's barriers
// blocked (R12: 75% stall, VALU 25%, elapsed 119K cy/block vs 30K cy issue).
// ---------------------------------------------------------------------------
__global__ __launch_bounds__(256, 4) void dcn_fused(
    const float* __restrict__ xh,      // (N, HW, C) fp32
    const float* __restrict__ offset,  // (N, 2*K, H, W)
    const float* __restrict__ mask,    // (N, K, H, W)
    const u16* __restrict__ wA3,       // (COUT, KK) bf16, k = tap*64+c
    const float* __restrict__ bias,
    float* __restrict__ out)           // (N, Cout, H, W)
{
    const int tid  = threadIdx.x;
    const int lane = tid & 63;
    const int wv   = tid >> 6;
    const int quad = lane >> 4;
    const int l16  = lane & 15;

    const int lb  = (blockIdx.x & 7) * 128 + (blockIdx.x >> 3);  // XCD swizzle
    const int pxb = lb * 64;                     // 64 | HW_: one image per block
    const int n   = pxb >> 14;
    const int hwb = (pxb & (HW_ - 1)) + wv * 16; // THIS WAVE's 16-pixel base

    __shared__ float coefw[4][144][8];           // 18.4 KB, per-wave slabs
    __shared__ u16   Bt[4][2][16][72];           // 18.4 KB, per-wave dbuf slabs

    // ---- phase 1: coefs for this wave's 16 px x 9 taps (no barrier) ----
#pragma unroll
    for (int rep = 0; rep < 3; ++rep) {
        const int e = rep * 64 + lane;
        if (e < 144) {
            const int p  = e / 9;                // 0..15 local pixel
            const int t  = e - p * 9;
            const int hw = hwb + p;
            const int ho = hw >> 7;
            const int wo = hw & (W_ - 1);
            const int ky = t / KW_;
            const int kx = t - ky * KW_;

            const float offy = offset[n * (2 * K_ * HW_) + (2 * t + 0) * HW_ + hw];
            const float offx = offset[n * (2 * K_ * HW_) + (2 * t + 1) * HW_ + hw];
            const float mval = mask[n * (K_ * HW_) + t * HW_ + hw];

            const float py = (float)(ho - 1 + ky) + offy;   // stride=1,pad=1,dil=1
            const float qx = (float)(wo - 1 + kx) + offx;
            const float y0f = floorf(py), x0f = floorf(qx);
            const float ly = py - y0f, lx = qx - x0f;
            const int y0 = (int)y0f, x0 = (int)x0f;
            const int y1 = y0 + 1,   x1 = x0 + 1;
            const bool vy0 = (y0 >= 0) & (y0 < H_);
            const bool vy1 = (y1 >= 0) & (y1 < H_);
            const bool vx0 = (x0 >= 0) & (x0 < W_);
            const bool vx1 = (x1 >= 0) & (x1 < W_);
            const int cy0 = min(max(y0, 0), H_ - 1);
            const int cy1 = min(max(y1, 0), H_ - 1);
            const int cx0 = min(max(x0, 0), W_ - 1);
            const int cx1 = min(max(x1, 0), W_ - 1);

            float* q = &coefw[wv][e][0];
            q[0] = (1.f - ly) * (1.f - lx) * mval * ((vy0 && vx0) ? 1.f : 0.f);
            q[1] = (1.f - ly) * lx         * mval * ((vy0 && vx1) ? 1.f : 0.f);
            q[2] = ly         * (1.f - lx) * mval * ((vy1 && vx0) ? 1.f : 0.f);
            q[3] = ly         * lx         * mval * ((vy1 && vx1) ? 1.f : 0.f);
            int* qi = (int*)q;
            qi[4] = cy0 * W_ + cx0;
            qi[5] = cy0 * W_ + cx1;
            qi[6] = cy1 * W_ + cx0;
            qi[7] = cy1 * W_ + cx1;
        }
    }
    // wave-local LDS write->read: in-order DS + compiler lgkmcnt, no barrier.

    // gather identity: quarter-wave per pixel, 4 channels per lane
    const int qtr = quad;                        // pixel within group of 4
    const int c4  = l16;                         // channel quad: 4c4..4c4+3
    const float* xb4 = xh + ((size_t)n * HW_) * 64 + 4 * c4;

    v4f acc[4];
#pragma unroll
    for (int mh = 0; mh < 4; ++mh) acc[mh] = (v4f){0.f, 0.f, 0.f, 0.f};

#pragma unroll
    for (int t = 0; t < K_; ++t) {
        const int buf = t & 1;

        // ---- gather tap t into this wave's Bt[buf] ----
#pragma unroll
        for (int i = 0; i < 4; ++i) {
            const int p = 4 * i + qtr;           // local pixel 0..15
            const float* q = &coefw[wv][p * 9 + t][0];
            const v4f f = *(const v4f*)q;
            const v4i o = *(const v4i*)(q + 4);
            const v4f v00 = *(const v4f*)(xb4 + (size_t)o.x * 64);
            const v4f v01 = *(const v4f*)(xb4 + (size_t)o.y * 64);
            const v4f v10 = *(const v4f*)(xb4 + (size_t)o.z * 64);
            const v4f v11 = *(const v4f*)(xb4 + (size_t)o.w * 64);
            const float r0 = fmaf(f.x, v00.x, fmaf(f.y, v01.x,
                             fmaf(f.z, v10.x, f.w * v11.x)));
            const float r1 = fmaf(f.x, v00.y, fmaf(f.y, v01.y,
                             fmaf(f.z, v10.y, f.w * v11.y)));
            const float r2 = fmaf(f.x, v00.z, fmaf(f.y, v01.z,
                             fmaf(f.z, v10.z, f.w * v11.z)));
            const float r3 = fmaf(f.x, v00.w, fmaf(f.y, v01.w,
                             fmaf(f.z, v10.w, f.w * v11.w)));
            v2u pk;
            pk.x = pack2(r0, r1);
            pk.y = pack2(r2, r3);
            *(v2u*)&Bt[wv][buf][p][4 * c4] = pk;
        }

        // ---- MFMA tap t: 2 k-chunks x 4 cout-subtiles ----
#pragma unroll
        for (int kc = 0; kc < 2; ++kc) {
            const v8s bfr = *(const v8s*)&Bt[wv][buf][l16][kc * 32 + quad * 8];
#pragma unroll
            for (int mh = 0; mh < 4; ++mh) {
                const v8s afr = *(const v8s*)(wA3 + (size_t)(mh * 16 + l16) * KK_
                                              + t * 64 + kc * 32 + quad * 8);
                acc[mh] = __builtin_amdgcn_mfma_f32_16x16x32_bf16(
                    afr, bfr, acc[mh], 0, 0, 0);
            }
        }
    }

    // D layout (R4-verified): col = l16 (px), row = quad*4 + r (cout)
    float* outb = out + n * (COUT_ * HW_);
#pragma unroll
    for (int mh = 0; mh < 4; ++mh)
#pragma unroll
        for (int r = 0; r < 4; ++r) {
            const int m = mh * 16 + quad * 4 + r;
            outb[m * HW_ + hwb + l16] = acc[mh][r] + bias[m];
        }
}

// ---------------------------------------------------------------------------
// Fallback (ws too small): R3-style direct fp32 kernel, no ws needed.
// ---------------------------------------------------------------------------
__global__ __launch_bounds__(256) void dcn_fallback(
    const float* __restrict__ x, const float* __restrict__ offset,
    const float* __restrict__ mask, const float* __restrict__ wptr,
    const float* __restrict__ bias, float* __restrict__ out)
{
    const int pix = blockIdx.x * 256 + threadIdx.x;
    const int n = pix >> 14, hw = pix & (HW_ - 1);
    const int ho = hw >> 7,  wo = hw & (W_ - 1);
    float acc[COUT_];
#pragma unroll
    for (int o = 0; o < COUT_; ++o) acc[o] = bias[o];
    const float* xn   = x + n * (C_ * HW_);
    const float* offn = offset + n * (2 * K_ * HW_) + hw;
    const float* mn   = mask + n * (K_ * HW_) + hw;
    for (int ct = 0; ct < C_; ct += 8) {
        for (int k = 0; k < K_; ++k) {
            const int ky = k / KW_, kx = k - ky * KW_;
            const float off_y = offn[(2 * k + 0) * HW_];
            const float off_x = offn[(2 * k + 1) * HW_];
            const float m = mn[k * HW_];
            const float py = (float)(ho - 1 + ky) + off_y;
            const float px = (float)(wo - 1 + kx) + off_x;
            const float y0f = floorf(py), x0f = floorf(px);
            const float ly = py - y0f, lx = px - x0f;
            const int y0 = (int)y0f, x0 = (int)x0f, y1 = y0 + 1, x1 = x0 + 1;
            const bool vy0 = (y0 >= 0) & (y0 < H_), vy1 = (y1 >= 0) & (y1 < H_);
            const bool vx0 = (x0 >= 0) & (x0 < W_), vx1 = (x1 >= 0) & (x1 < W_);
            const int cy0 = min(max(y0, 0), H_ - 1), cy1 = min(max(y1, 0), H_ - 1);
            const int cx0 = min(max(x0, 0), W_ - 1), cx1 = min(max(x1, 0), W_ - 1);
            const int i00 = cy0 * W_ + cx0, i01 = cy0 * W_ + cx1;
            const int i10 = cy1 * W_ + cx0, i11 = cy1 * W_ + cx1;
            const float f00 = (1.f - ly) * (1.f - lx) * m * ((vy0 && vx0) ? 1.f : 0.f);
            const float f01 = (1.f - ly) * lx * m * ((vy0 && vx1) ? 1.f : 0.f);
            const float f10 = ly * (1.f - lx) * m * ((vy1 && vx0) ? 1.f : 0.f);
            const float f11 = ly * lx * m * ((vy1 && vx1) ? 1.f : 0.f);
            for (int cc = 0; cc < 8; ++cc) {
                const int c = ct + cc;
                const float* xc = xn + c * HW_;
                const float val = fmaf(f00, xc[i00], fmaf(f01, xc[i01],
                                  fmaf(f10, xc[i10], f11 * xc[i11])));
#pragma unroll
                for (int o = 0; o < COUT_; ++o)
                    acc[o] = fmaf(wptr[o * (C_ * K_) + c * K_ + k], val, acc[o]);
            }
        }
    }
    float* outp = out + n * (COUT_ * HW_) + hw;
#pragma unroll
    for (int o = 0; o < COUT_; ++o) outp[o * HW_] = acc[o];
}

extern "C" void kernel_launch(void* const* d_in, const int* in_sizes, int n_in,
                              void* d_out, int out_size, void* d_ws, size_t ws_size,
                              hipStream_t stream) {
    const float* x      = (const float*)d_in[0];
    const float* offset = (const float*)d_in[1];
    const float* mask   = (const float*)d_in[2];
    const float* weight = (const float*)d_in[3];
    const float* bias   = (const float*)d_in[4];
    float* out = (float*)d_out;

    const size_t xh_bytes = (size_t)NPIX * C_ * sizeof(float);     // 16.8 MB
    const size_t wA_bytes = (size_t)COUT_ * KK_ * sizeof(u16);     // 73.7 KB

    if (ws_size >= xh_bytes + wA_bytes) {
        float* xh  = (float*)d_ws;
        u16*   wA3 = (u16*)((char*)d_ws + xh_bytes);
        prep<<<1024 + 144, 256, 0, stream>>>(x, xh, weight, wA3);
        dcn_fused<<<NPIX / 64, 256, 0, stream>>>(xh, offset, mask, wA3, bias, out);
    } else {
        dcn_fallback<<<NPIX / 256, 256, 0, stream>>>(x, offset, mask, weight, bias, out);
    }
}